// Round 4
// baseline (579.354 us; speedup 1.0000x reference)
//
#include <hip/hip_runtime.h>
#include <hip/hip_bf16.h>

typedef __attribute__((ext_vector_type(8))) short short8;
typedef __attribute__((ext_vector_type(4))) float floatx4;
typedef unsigned int u32;

__device__ __forceinline__ float bf2f(u32 u) {
    union { u32 u; float f; } c; c.u = u << 16; return c.f;
}
__device__ __forceinline__ float bf2f_hi(u32 u) {
    union { u32 u; float f; } c; c.u = u & 0xFFFF0000u; return c.f;
}
__device__ __forceinline__ u32 f2bf(float f) {
    union { float f; u32 u; } c; c.f = f;
    return (c.u + 0x7FFFu + ((c.u >> 16) & 1u)) >> 16;  // RNE
}
__device__ __forceinline__ short8 cvt8(const float* p) {
    float4 f0 = ((const float4*)p)[0];
    float4 f1 = ((const float4*)p)[1];
    short8 r;
    r[0] = (short)f2bf(f0.x); r[1] = (short)f2bf(f0.y);
    r[2] = (short)f2bf(f0.z); r[3] = (short)f2bf(f0.w);
    r[4] = (short)f2bf(f1.x); r[5] = (short)f2bf(f1.y);
    r[6] = (short)f2bf(f1.z); r[7] = (short)f2bf(f1.w);
    return r;
}

// ---------------- CSR build: bucket sort (256 dst nodes / bucket) ----------------
__global__ __launch_bounds__(256) void hist_k(const int* __restrict__ dst,
                                              int* __restrict__ bcnt, int E) {
    __shared__ int h[512];
    int t = threadIdx.x;
    h[t] = 0; h[t + 256] = 0;
    __syncthreads();
    int e0 = blockIdx.x * 4096;
    int ne = min(4096, E - e0);
    for (int i = t; i < ne; i += 256) atomicAdd(&h[dst[e0 + i] >> 8], 1);
    __syncthreads();
    int c = h[t];
    if (c) atomicAdd(&bcnt[t], c);
    c = h[t + 256];
    if (c) atomicAdd(&bcnt[t + 256], c);
}

__global__ void bscan_k(const int* __restrict__ bcnt, int* __restrict__ bbase,
                        int* __restrict__ cursor, int nb, int E) {
    __shared__ int tmp[512];
    int t = threadIdx.x;
    int v = (t < nb) ? bcnt[t] : 0;
    tmp[t] = v;
    __syncthreads();
    for (int off = 1; off < 512; off <<= 1) {
        int a = (t >= off) ? tmp[t - off] : 0;
        __syncthreads();
        tmp[t] += a;
        __syncthreads();
    }
    if (t < nb) {
        int ex = tmp[t] - v;
        bbase[t] = ex;
        cursor[t] = ex;
    }
    if (t == 0) bbase[nb] = E;
}

// direct grouped writes to reserved per-bucket ranges (no LDS staging / binsearch)
__global__ __launch_bounds__(256) void bucket_k(const int* __restrict__ src,
                                                const int* __restrict__ dst,
                                                int* __restrict__ cursor,
                                                u32* __restrict__ pairs, int E, int nb) {
    __shared__ int cnt[512];
    __shared__ int gbase[512];
    __shared__ int cur[512];
    int t = threadIdx.x;
    cnt[t] = 0; cnt[t + 256] = 0;
    __syncthreads();
    int e0 = blockIdx.x * 8192;
    int ne = min(8192, E - e0);
    for (int i = t; i < ne; i += 256) atomicAdd(&cnt[dst[e0 + i] >> 8], 1);
    __syncthreads();
    for (int b = t; b < nb; b += 256) {
        int c = cnt[b];
        gbase[b] = c ? atomicAdd(&cursor[b], c) : 0;
        cur[b] = 0;
    }
    __syncthreads();
    for (int i = t; i < ne; i += 256) {
        int d = dst[e0 + i];
        int s = src[e0 + i];
        int b = d >> 8;
        int p = atomicAdd(&cur[b], 1);
        pairs[gbase[b] + p] = (u32)s | ((u32)(d & 255) << 24);
    }
}

// per-bucket rowptr/dinv/col build + per-node src-sort (temporal locality for agg)
#define LCOL_CAP 12288
__global__ __launch_bounds__(256) void build_k(const u32* __restrict__ pairs,
                                               const int* __restrict__ bbase,
                                               int* __restrict__ rowptr,
                                               float* __restrict__ dinv,
                                               int* __restrict__ col, int N, int E) {
    __shared__ int cnt[256], incl[256], cur[256];
    __shared__ int lcol[LCOL_CAP];
    int b = blockIdx.x, t = threadIdx.x;
    int base = bbase[b];
    int ecnt = bbase[b + 1] - base;
    cnt[t] = 0;
    __syncthreads();
    for (int j = t; j < ecnt; j += 256) atomicAdd(&cnt[pairs[base + j] >> 24], 1);
    __syncthreads();
    incl[t] = cnt[t];
    __syncthreads();
    for (int off = 1; off < 256; off <<= 1) {
        int a = (t >= off) ? incl[t - off] : 0;
        __syncthreads();
        incl[t] += a;
        __syncthreads();
    }
    int myc = cnt[t];
    int ex = incl[t] - myc;
    int node = b * 256 + t;
    if (node < N) {
        rowptr[node] = base + ex;
        dinv[node] = rsqrtf((float)myc + 1.0f);  // +1 self-loop
    }
    cur[t] = ex;
    if (b == 0 && t == 0) rowptr[N] = E;
    __syncthreads();
    if (ecnt <= LCOL_CAP) {
        for (int j = t; j < ecnt; j += 256) {
            u32 v = pairs[base + j];
            int r = atomicAdd(&cur[v >> 24], 1);
            lcol[r] = (int)(v & 0xFFFFFF);
        }
        __syncthreads();
        // insertion-sort my node's segment [ex, ex+myc)
        for (int i = ex + 1; i < ex + myc; ++i) {
            int key = lcol[i];
            int j = i - 1;
            while (j >= ex && lcol[j] > key) { lcol[j + 1] = lcol[j]; --j; }
            lcol[j + 1] = key;
        }
        __syncthreads();
        for (int j = t; j < ecnt; j += 256) col[base + j] = lcol[j];
    } else {  // safety fallback (can't happen for uniform random input)
        for (int j = t; j < ecnt; j += 256) {
            u32 v = pairs[base + j];
            int r = atomicAdd(&cur[v >> 24], 1);
            col[base + r] = (int)(v & 0xFFFFFF);
        }
    }
}

// fused transpose + f32->bf16 for all 5 weight matrices
__global__ void transcvt_k(const float* __restrict__ W1, const float* __restrict__ W2,
                           const float* __restrict__ W3, const float* __restrict__ Wp1,
                           const float* __restrict__ Wp2,
                           unsigned short* __restrict__ o1, unsigned short* __restrict__ o2,
                           unsigned short* __restrict__ o3, unsigned short* __restrict__ o4,
                           unsigned short* __restrict__ o5) {
    int i = blockIdx.x * 256 + threadIdx.x;
    const float* in; unsigned short* out; int cols, li;
    if (i < 16384)      { in = W1;  out = o1; cols = 128; li = i; }
    else if (i < 32768) { in = W2;  out = o2; cols = 128; li = i - 16384; }
    else if (i < 49152) { in = W3;  out = o3; cols = 128; li = i - 32768; }
    else if (i < 65536) { in = Wp1; out = o4; cols = 128; li = i - 49152; }
    else                { in = Wp2; out = o5; cols = 64;  li = i - 65536; }
    int r = li / cols, c = li - r * cols;
    out[(size_t)c * 128 + r] = (unsigned short)f2bf(in[li]);
}

// ---------------- GEMM: out[M][NCOLS] = A[M][128] @ W[128][NCOLS] (Wt bf16, pre-T) ----------------
template <int NCOLS, bool BIAS, bool SIG, bool AF32, bool OUTF32, bool DINV>
__global__ __launch_bounds__(256) void gemm_k(const void* __restrict__ Av,
                                              const short* __restrict__ Wt,
                                              const float* __restrict__ bias,
                                              const float* __restrict__ dinv,
                                              void* __restrict__ outv, int M) {
    int wave = threadIdx.x >> 6;
    int lane = threadIdx.x & 63;
    int m0 = blockIdx.x * 64 + wave * 16;
    if (m0 >= M) return;
    int quad = lane >> 4, lr = lane & 15;
    int row = m0 + lr;
    if (row >= M) row = M - 1;  // clamp loads; stores guarded
    short8 a0, a1, a2, a3;
    if (AF32) {
        const float* Ab = (const float*)Av + (size_t)row * 128 + quad * 8;
        a0 = cvt8(Ab); a1 = cvt8(Ab + 32); a2 = cvt8(Ab + 64); a3 = cvt8(Ab + 96);
    } else {
        const short8* Ap = (const short8*)((const short*)Av + (size_t)row * 128 + quad * 8);
        a0 = Ap[0]; a1 = Ap[4]; a2 = Ap[8]; a3 = Ap[12];
    }
#pragma unroll
    for (int nt = 0; nt < NCOLS / 16; ++nt) {
        int ncol = nt * 16 + lr;
        const short8* Bp = (const short8*)(Wt + (size_t)ncol * 128 + quad * 8);
        short8 b0 = Bp[0], b1 = Bp[4], b2 = Bp[8], b3 = Bp[12];
        floatx4 acc = {0.f, 0.f, 0.f, 0.f};
        acc = __builtin_amdgcn_mfma_f32_16x16x32_bf16(a0, b0, acc, 0, 0, 0);
        acc = __builtin_amdgcn_mfma_f32_16x16x32_bf16(a1, b1, acc, 0, 0, 0);
        acc = __builtin_amdgcn_mfma_f32_16x16x32_bf16(a2, b2, acc, 0, 0, 0);
        acc = __builtin_amdgcn_mfma_f32_16x16x32_bf16(a3, b3, acc, 0, 0, 0);
        float bv = BIAS ? bias[ncol] : 0.f;
#pragma unroll
        for (int r = 0; r < 4; ++r) {
            int orow = m0 + quad * 4 + r;  // D: col=lane&15, row=quad*4+r
            if (orow < M) {
                float v = acc[r];
                if (DINV) v *= dinv[orow];
                v += bv;
                if (SIG) v = 1.f / (1.f + __expf(-v));
                if (OUTF32)
                    ((float*)outv)[(size_t)orow * NCOLS + ncol] = v;
                else
                    ((unsigned short*)outv)[(size_t)orow * NCOLS + ncol] =
                        (unsigned short)f2bf(v);
            }
        }
    }
}

// ---------------- fused aggregate + bias + relu (+ LayerNorm), v2 ----------------
// wave per node; 16 lanes per row (dwordx4 each), 4 edges in flight per batch.
// hw rows pre-scaled by dinv[src]; out = dinv[i]*(sum_neighbors + self) + b
template <int MODE>  // 0: relu+LN, 1: relu only
__global__ __launch_bounds__(256) void agg_k(const u32* __restrict__ hw,
                                             const int* __restrict__ rowptr,
                                             const int* __restrict__ col,
                                             const float* __restrict__ dinv,
                                             const float* __restrict__ bias,
                                             const float* __restrict__ gam,
                                             const float* __restrict__ bet,
                                             u32* __restrict__ out, int n) {
    int lane = threadIdx.x & 63;
    int node = blockIdx.x * 4 + (threadIdx.x >> 6);
    if (node >= n) return;
    int g = lane >> 4, r = lane & 15;
    int beg = rowptr[node], end = rowptr[node + 1];
    float acc[8] = {0.f, 0.f, 0.f, 0.f, 0.f, 0.f, 0.f, 0.f};
    for (int c = beg; c < end; c += 64) {
        int m = end - c;
        if (m > 64) m = 64;
        int sv = (c + lane < end) ? col[c + lane] : 0;
        int fb = m >> 2;
        for (int b = 0; b < fb; ++b) {
            int s = __shfl(sv, b * 4 + g);
            uint4 v = *(const uint4*)(hw + (size_t)s * 64 + r * 4);
            acc[0] += bf2f(v.x); acc[1] += bf2f_hi(v.x);
            acc[2] += bf2f(v.y); acc[3] += bf2f_hi(v.y);
            acc[4] += bf2f(v.z); acc[5] += bf2f_hi(v.z);
            acc[6] += bf2f(v.w); acc[7] += bf2f_hi(v.w);
        }
        int tl = m & 3;
        if (tl) {
            int s = __shfl(sv, fb * 4 + g);
            if (g < tl) {
                uint4 v = *(const uint4*)(hw + (size_t)s * 64 + r * 4);
                acc[0] += bf2f(v.x); acc[1] += bf2f_hi(v.x);
                acc[2] += bf2f(v.y); acc[3] += bf2f_hi(v.y);
                acc[4] += bf2f(v.z); acc[5] += bf2f_hi(v.z);
                acc[6] += bf2f(v.w); acc[7] += bf2f_hi(v.w);
            }
        }
    }
    {   // self term (group 0 only; pre-combine)
        uint4 v = *(const uint4*)(hw + (size_t)node * 64 + r * 4);
        if (g == 0) {
            acc[0] += bf2f(v.x); acc[1] += bf2f_hi(v.x);
            acc[2] += bf2f(v.y); acc[3] += bf2f_hi(v.y);
            acc[4] += bf2f(v.z); acc[5] += bf2f_hi(v.z);
            acc[6] += bf2f(v.w); acc[7] += bf2f_hi(v.w);
        }
    }
#pragma unroll
    for (int k = 0; k < 8; ++k) {  // combine the 4 groups
        acc[k] += __shfl_xor(acc[k], 16, 64);
        acc[k] += __shfl_xor(acc[k], 32, 64);
    }
    float di = dinv[node];
    float4 bA = ((const float4*)(bias + r * 8))[0];
    float4 bB = ((const float4*)(bias + r * 8))[1];
    acc[0] = fmaxf(di * acc[0] + bA.x, 0.f);
    acc[1] = fmaxf(di * acc[1] + bA.y, 0.f);
    acc[2] = fmaxf(di * acc[2] + bA.z, 0.f);
    acc[3] = fmaxf(di * acc[3] + bA.w, 0.f);
    acc[4] = fmaxf(di * acc[4] + bB.x, 0.f);
    acc[5] = fmaxf(di * acc[5] + bB.y, 0.f);
    acc[6] = fmaxf(di * acc[6] + bB.z, 0.f);
    acc[7] = fmaxf(di * acc[7] + bB.w, 0.f);
    if (MODE == 0) {
        float s = 0.f, q = 0.f;
#pragma unroll
        for (int k = 0; k < 8; ++k) { s += acc[k]; q += acc[k] * acc[k]; }
#pragma unroll
        for (int m = 8; m >= 1; m >>= 1) {
            s += __shfl_xor(s, m, 64);
            q += __shfl_xor(q, m, 64);
        }
        float mu = s * (1.f / 128.f);
        float var = q * (1.f / 128.f) - mu * mu;
        float rs = rsqrtf(fmaxf(var, 0.f) + 1e-5f);
        float4 gA = ((const float4*)(gam + r * 8))[0];
        float4 gB = ((const float4*)(gam + r * 8))[1];
        float4 eA = ((const float4*)(bet + r * 8))[0];
        float4 eB = ((const float4*)(bet + r * 8))[1];
        acc[0] = gA.x * (acc[0] - mu) * rs + eA.x;
        acc[1] = gA.y * (acc[1] - mu) * rs + eA.y;
        acc[2] = gA.z * (acc[2] - mu) * rs + eA.z;
        acc[3] = gA.w * (acc[3] - mu) * rs + eA.w;
        acc[4] = gB.x * (acc[4] - mu) * rs + eB.x;
        acc[5] = gB.y * (acc[5] - mu) * rs + eB.y;
        acc[6] = gB.z * (acc[6] - mu) * rs + eB.z;
        acc[7] = gB.w * (acc[7] - mu) * rs + eB.w;
    }
    if (g == 0) {
        uint4 o;
        o.x = f2bf(acc[0]) | (f2bf(acc[1]) << 16);
        o.y = f2bf(acc[2]) | (f2bf(acc[3]) << 16);
        o.z = f2bf(acc[4]) | (f2bf(acc[5]) << 16);
        o.w = f2bf(acc[6]) | (f2bf(acc[7]) << 16);
        *(uint4*)(out + (size_t)node * 64 + r * 4) = o;
    }
}

extern "C" void kernel_launch(void* const* d_in, const int* in_sizes, int n_in,
                              void* d_out, int out_size, void* d_ws, size_t ws_size,
                              hipStream_t stream) {
    const int N = in_sizes[0] / 128;
    const int E = in_sizes[1] / 2;
    const int nb = (N + 255) >> 8;
    const int* edge = (const int*)d_in[1];
    const int* srcp = edge;
    const int* dstp = edge + E;
    const float* x   = (const float*)d_in[0];
    const float* W1  = (const float*)d_in[2];
    const float* b1  = (const float*)d_in[3];
    const float* W2  = (const float*)d_in[4];
    const float* b2  = (const float*)d_in[5];
    const float* W3  = (const float*)d_in[6];
    const float* b3  = (const float*)d_in[7];
    const float* g1  = (const float*)d_in[8];
    const float* be1 = (const float*)d_in[9];
    const float* g2  = (const float*)d_in[10];
    const float* be2 = (const float*)d_in[11];
    const float* Wp1 = (const float*)d_in[12];
    const float* bp1 = (const float*)d_in[13];
    const float* Wp2 = (const float*)d_in[14];
    const float* bp2 = (const float*)d_in[15];

    char* ws = (char*)d_ws;
    size_t off = 0;
    auto alloc = [&](size_t b) -> char* {
        char* p = ws + off;
        off += (b + 255) & ~(size_t)255;
        return p;
    };
    int* bcnt   = (int*)alloc(512 * 4);
    int* bbase  = (int*)alloc((size_t)(nb + 1) * 4);
    int* cursor = (int*)alloc((size_t)nb * 4);
    int* rowptr = (int*)alloc((size_t)(N + 1) * 4);
    float* dinv = (float*)alloc((size_t)N * 4);
    u32* pairs  = (u32*)alloc((size_t)E * 4);
    int* colA   = (int*)alloc((size_t)E * 4);
    unsigned short* hw  = (unsigned short*)alloc((size_t)N * 128 * 2);
    unsigned short* hb  = (unsigned short*)alloc((size_t)N * 128 * 2);
    unsigned short* w1t = (unsigned short*)alloc(128 * 128 * 2);
    unsigned short* w2t = (unsigned short*)alloc(128 * 128 * 2);
    unsigned short* w3t = (unsigned short*)alloc(128 * 128 * 2);
    unsigned short* wp1t = (unsigned short*)alloc(128 * 128 * 2);
    unsigned short* wp2t = (unsigned short*)alloc(64 * 128 * 2);
    if (off > ws_size) return;

    int gb = (N + 63) / 64;
    int ab = (N + 3) / 4;

    hipMemsetAsync(bcnt, 0, 512 * 4, stream);
    hist_k<<<(E + 4095) / 4096, 256, 0, stream>>>(dstp, bcnt, E);
    bscan_k<<<1, 512, 0, stream>>>(bcnt, bbase, cursor, nb, E);
    bucket_k<<<(E + 8191) / 8192, 256, 0, stream>>>(srcp, dstp, cursor, pairs, E, nb);
    build_k<<<nb, 256, 0, stream>>>(pairs, bbase, rowptr, dinv, colA, N, E);
    transcvt_k<<<288, 256, 0, stream>>>(W1, W2, W3, Wp1, Wp2, w1t, w2t, w3t, wp1t, wp2t);

    gemm_k<128, false, false, true, false, true><<<gb, 256, 0, stream>>>(
        x, (const short*)w1t, nullptr, dinv, hw, N);
    agg_k<0><<<ab, 256, 0, stream>>>((const u32*)hw, rowptr, colA, dinv, b1, g1, be1,
                                     (u32*)hb, N);
    gemm_k<128, false, false, false, false, true><<<gb, 256, 0, stream>>>(
        hb, (const short*)w2t, nullptr, dinv, hw, N);
    agg_k<0><<<ab, 256, 0, stream>>>((const u32*)hw, rowptr, colA, dinv, b2, g2, be2,
                                     (u32*)hb, N);
    gemm_k<128, false, false, false, false, true><<<gb, 256, 0, stream>>>(
        hb, (const short*)w3t, nullptr, dinv, hw, N);
    agg_k<1><<<ab, 256, 0, stream>>>((const u32*)hw, rowptr, colA, dinv, b3, g1, be1,
                                     (u32*)hb, N);
    gemm_k<128, true, false, false, false, false><<<gb, 256, 0, stream>>>(
        hb, (const short*)wp1t, bp1, nullptr, hw, N);
    gemm_k<64, true, true, false, true, false><<<gb, 256, 0, stream>>>(
        hw, (const short*)wp2t, bp2, nullptr, d_out, N);
}

// Round 5
// 504.688 us; speedup vs baseline: 1.1479x; 1.1479x over previous
//
#include <hip/hip_runtime.h>
#include <hip/hip_bf16.h>

typedef __attribute__((ext_vector_type(8))) short short8;
typedef __attribute__((ext_vector_type(4))) float floatx4;
typedef unsigned int u32;

__device__ __forceinline__ float bf2f(u32 u) {
    union { u32 u; float f; } c; c.u = u << 16; return c.f;
}
__device__ __forceinline__ float bf2f_hi(u32 u) {
    union { u32 u; float f; } c; c.u = u & 0xFFFF0000u; return c.f;
}
__device__ __forceinline__ u32 f2bf(float f) {
    union { float f; u32 u; } c; c.f = f;
    return (c.u + 0x7FFFu + ((c.u >> 16) & 1u)) >> 16;  // RNE
}
__device__ __forceinline__ short8 cvt8(const float* p) {
    float4 f0 = ((const float4*)p)[0];
    float4 f1 = ((const float4*)p)[1];
    short8 r;
    r[0] = (short)f2bf(f0.x); r[1] = (short)f2bf(f0.y);
    r[2] = (short)f2bf(f0.z); r[3] = (short)f2bf(f0.w);
    r[4] = (short)f2bf(f1.x); r[5] = (short)f2bf(f1.y);
    r[6] = (short)f2bf(f1.z); r[7] = (short)f2bf(f1.w);
    return r;
}

// ---------------- CSR build: bucket sort (256 dst nodes / bucket) ----------------
__global__ __launch_bounds__(256) void hist_k(const int* __restrict__ dst,
                                              int* __restrict__ bcnt, int E) {
    __shared__ int h[512];
    int t = threadIdx.x;
    h[t] = 0; h[t + 256] = 0;
    __syncthreads();
    int e0 = blockIdx.x * 4096;
    int ne = min(4096, E - e0);
    for (int i = t; i < ne; i += 256) atomicAdd(&h[dst[e0 + i] >> 8], 1);
    __syncthreads();
    int c = h[t];
    if (c) atomicAdd(&bcnt[t], c);
    c = h[t + 256];
    if (c) atomicAdd(&bcnt[t + 256], c);
}

__global__ void bscan_k(const int* __restrict__ bcnt, int* __restrict__ bbase,
                        int* __restrict__ cursor, int nb, int E) {
    __shared__ int tmp[512];
    int t = threadIdx.x;
    int v = (t < nb) ? bcnt[t] : 0;
    tmp[t] = v;
    __syncthreads();
    for (int off = 1; off < 512; off <<= 1) {
        int a = (t >= off) ? tmp[t - off] : 0;
        __syncthreads();
        tmp[t] += a;
        __syncthreads();
    }
    if (t < nb) {
        int ex = tmp[t] - v;
        bbase[t] = ex;
        cursor[t] = ex;
    }
    if (t == 0) bbase[nb] = E;
}

__global__ __launch_bounds__(256) void bucket_k(const int* __restrict__ src,
                                                const int* __restrict__ dst,
                                                int* __restrict__ cursor,
                                                u32* __restrict__ pairs, int E, int nb) {
    __shared__ int cnt[512];
    __shared__ int gbase[512];
    __shared__ int cur[512];
    int t = threadIdx.x;
    cnt[t] = 0; cnt[t + 256] = 0;
    __syncthreads();
    int e0 = blockIdx.x * 8192;
    int ne = min(8192, E - e0);
    for (int i = t; i < ne; i += 256) atomicAdd(&cnt[dst[e0 + i] >> 8], 1);
    __syncthreads();
    for (int b = t; b < nb; b += 256) {
        int c = cnt[b];
        gbase[b] = c ? atomicAdd(&cursor[b], c) : 0;
        cur[b] = 0;
    }
    __syncthreads();
    for (int i = t; i < ne; i += 256) {
        int d = dst[e0 + i];
        int s = src[e0 + i];
        int b = d >> 8;
        int p = atomicAdd(&cur[b], 1);
        pairs[gbase[b] + p] = (u32)s | ((u32)(d & 255) << 24);
    }
}

// per-bucket rowptr/dinv/col build (LDS-staged for grouped coalesced writes)
#define LCOL_CAP 12288
__global__ __launch_bounds__(256) void build_k(const u32* __restrict__ pairs,
                                               const int* __restrict__ bbase,
                                               int* __restrict__ rowptr,
                                               float* __restrict__ dinv,
                                               int* __restrict__ col, int N, int E) {
    __shared__ int cnt[256], incl[256], cur[256];
    __shared__ int lcol[LCOL_CAP];
    int b = blockIdx.x, t = threadIdx.x;
    int base = bbase[b];
    int ecnt = bbase[b + 1] - base;
    cnt[t] = 0;
    __syncthreads();
    for (int j = t; j < ecnt; j += 256) atomicAdd(&cnt[pairs[base + j] >> 24], 1);
    __syncthreads();
    incl[t] = cnt[t];
    __syncthreads();
    for (int off = 1; off < 256; off <<= 1) {
        int a = (t >= off) ? incl[t - off] : 0;
        __syncthreads();
        incl[t] += a;
        __syncthreads();
    }
    int myc = cnt[t];
    int ex = incl[t] - myc;
    int node = b * 256 + t;
    if (node < N) {
        rowptr[node] = base + ex;
        dinv[node] = rsqrtf((float)myc + 1.0f);  // +1 self-loop
    }
    cur[t] = ex;
    if (b == 0 && t == 0) rowptr[N] = E;
    __syncthreads();
    if (ecnt <= LCOL_CAP) {
        for (int j = t; j < ecnt; j += 256) {
            u32 v = pairs[base + j];
            int r = atomicAdd(&cur[v >> 24], 1);
            lcol[r] = (int)(v & 0xFFFFFF);
        }
        __syncthreads();
        for (int j = t; j < ecnt; j += 256) col[base + j] = lcol[j];
    } else {  // safety fallback
        for (int j = t; j < ecnt; j += 256) {
            u32 v = pairs[base + j];
            int r = atomicAdd(&cur[v >> 24], 1);
            col[base + r] = (int)(v & 0xFFFFFF);
        }
    }
}

// fused transpose + f32->bf16 for all 5 weight matrices
__global__ void transcvt_k(const float* __restrict__ W1, const float* __restrict__ W2,
                           const float* __restrict__ W3, const float* __restrict__ Wp1,
                           const float* __restrict__ Wp2,
                           unsigned short* __restrict__ o1, unsigned short* __restrict__ o2,
                           unsigned short* __restrict__ o3, unsigned short* __restrict__ o4,
                           unsigned short* __restrict__ o5) {
    int i = blockIdx.x * 256 + threadIdx.x;
    const float* in; unsigned short* out; int cols, li;
    if (i < 16384)      { in = W1;  out = o1; cols = 128; li = i; }
    else if (i < 32768) { in = W2;  out = o2; cols = 128; li = i - 16384; }
    else if (i < 49152) { in = W3;  out = o3; cols = 128; li = i - 32768; }
    else if (i < 65536) { in = Wp1; out = o4; cols = 128; li = i - 49152; }
    else                { in = Wp2; out = o5; cols = 64;  li = i - 65536; }
    int r = li / cols, c = li - r * cols;
    out[(size_t)c * 128 + r] = (unsigned short)f2bf(in[li]);
}

// ---------------- GEMM: out[M][NCOLS] = A[M][128] @ W[128][NCOLS] (Wt bf16, pre-T) ----------------
// Operand-swapped MFMA: A-operand = Wt tile, B-operand = x rows -> C[m=ncol][n=xrow].
// Lane lr = output row; quad*4+r = 4 CONSECUTIVE output cols -> vectorized stores.
template <int NCOLS, bool BIAS, bool SIG, bool AF32, bool OUTF32, bool DINV>
__global__ __launch_bounds__(256) void gemm_k(const void* __restrict__ Av,
                                              const short* __restrict__ Wt,
                                              const float* __restrict__ bias,
                                              const float* __restrict__ dinv,
                                              void* __restrict__ outv, int M) {
    int wave = threadIdx.x >> 6;
    int lane = threadIdx.x & 63;
    int m0 = blockIdx.x * 64 + wave * 16;
    if (m0 >= M) return;
    int quad = lane >> 4, lr = lane & 15;
    int row = m0 + lr;
    bool wr = row < M;
    if (row >= M) row = M - 1;  // clamp loads; stores guarded by wr
    short8 b0, b1, b2, b3;      // B-operand: x row fragments
    if (AF32) {
        const float* Ab = (const float*)Av + (size_t)row * 128 + quad * 8;
        b0 = cvt8(Ab); b1 = cvt8(Ab + 32); b2 = cvt8(Ab + 64); b3 = cvt8(Ab + 96);
    } else {
        const short8* Ap = (const short8*)((const short*)Av + (size_t)row * 128 + quad * 8);
        b0 = Ap[0]; b1 = Ap[4]; b2 = Ap[8]; b3 = Ap[12];
    }
    float di = DINV ? dinv[row] : 1.f;
#pragma unroll
    for (int nt = 0; nt < NCOLS / 16; ++nt) {
        int ncol = nt * 16 + lr;
        const short8* Wp = (const short8*)(Wt + (size_t)ncol * 128 + quad * 8);
        short8 a0 = Wp[0], a1 = Wp[4], a2 = Wp[8], a3 = Wp[12];
        floatx4 acc = {0.f, 0.f, 0.f, 0.f};
        acc = __builtin_amdgcn_mfma_f32_16x16x32_bf16(a0, b0, acc, 0, 0, 0);
        acc = __builtin_amdgcn_mfma_f32_16x16x32_bf16(a1, b1, acc, 0, 0, 0);
        acc = __builtin_amdgcn_mfma_f32_16x16x32_bf16(a2, b2, acc, 0, 0, 0);
        acc = __builtin_amdgcn_mfma_f32_16x16x32_bf16(a3, b3, acc, 0, 0, 0);
        int c0 = nt * 16 + quad * 4;  // 4 consecutive cols for this lane
        float o[4];
#pragma unroll
        for (int r = 0; r < 4; ++r) {
            float v = acc[r] * di;
            if (BIAS) v += bias[c0 + r];
            if (SIG) v = 1.f / (1.f + __expf(-v));
            o[r] = v;
        }
        if (wr) {
            if (OUTF32) {
                float4 st = {o[0], o[1], o[2], o[3]};
                *(float4*)((float*)outv + (size_t)(m0 + lr) * NCOLS + c0) = st;
            } else {
                uint2 st;
                st.x = f2bf(o[0]) | (f2bf(o[1]) << 16);
                st.y = f2bf(o[2]) | (f2bf(o[3]) << 16);
                *(uint2*)((unsigned short*)outv + (size_t)(m0 + lr) * NCOLS + c0) = st;
            }
        }
    }
}

// ---------------- fused aggregate + bias + relu (+ LayerNorm), v3 ----------------
// wave per node; lane handles feats {2*lane, 2*lane+1} (one dword of the bf16 row);
// 16 gathers in flight; float2 packed accumulate (v_pk_add_f32).
// hw rows pre-scaled by dinv[src]; out = dinv[i]*(sum_neighbors + self) + b
template <int MODE>  // 0: relu+LN, 1: relu only
__global__ __launch_bounds__(256) void agg_k(const u32* __restrict__ hw,
                                             const int* __restrict__ rowptr,
                                             const int* __restrict__ col,
                                             const float* __restrict__ dinv,
                                             const float* __restrict__ bias,
                                             const float* __restrict__ gam,
                                             const float* __restrict__ bet,
                                             u32* __restrict__ out, int n) {
    int lane = threadIdx.x & 63;
    int node = blockIdx.x * 4 + (threadIdx.x >> 6);
    if (node >= n) return;
    int beg = rowptr[node], end = rowptr[node + 1];
    float2 acc = {0.f, 0.f};
    for (int c = beg; c < end; c += 64) {
        int idx = c + lane;
        int sv = (idx < end) ? col[idx] : 0;
        int m = end - c;
        if (m > 64) m = 64;
        int e = 0;
        for (; e + 16 <= m; e += 16) {  // 16 gathers in flight
            u32 v[16];
#pragma unroll
            for (int j = 0; j < 16; ++j) {
                int s = __shfl(sv, e + j);
                v[j] = hw[(size_t)s * 64 + lane];
            }
#pragma unroll
            for (int j = 0; j < 16; ++j) {
                float2 p = {bf2f(v[j] & 0xffff), bf2f_hi(v[j])};
                acc.x += p.x; acc.y += p.y;
            }
        }
        for (; e + 4 <= m; e += 4) {
            u32 v[4];
#pragma unroll
            for (int j = 0; j < 4; ++j) {
                int s = __shfl(sv, e + j);
                v[j] = hw[(size_t)s * 64 + lane];
            }
#pragma unroll
            for (int j = 0; j < 4; ++j) {
                float2 p = {bf2f(v[j] & 0xffff), bf2f_hi(v[j])};
                acc.x += p.x; acc.y += p.y;
            }
        }
        for (; e < m; ++e) {
            int s = __shfl(sv, e);
            u32 v = hw[(size_t)s * 64 + lane];
            acc.x += bf2f(v & 0xffff);
            acc.y += bf2f_hi(v);
        }
    }
    float di = dinv[node];
    u32 vs = hw[(size_t)node * 64 + lane];  // self (already dinv[i]-scaled)
    float a0 = di * (acc.x + bf2f(vs & 0xffff));
    float a1 = di * (acc.y + bf2f_hi(vs));
    a0 = fmaxf(a0 + bias[2 * lane], 0.f);
    a1 = fmaxf(a1 + bias[2 * lane + 1], 0.f);
    if (MODE == 0) {
        float s = a0 + a1, q = a0 * a0 + a1 * a1;
#pragma unroll
        for (int m = 32; m >= 1; m >>= 1) {
            s += __shfl_xor(s, m, 64);
            q += __shfl_xor(q, m, 64);
        }
        float mu = s * (1.f / 128.f);
        float var = q * (1.f / 128.f) - mu * mu;
        float rs = rsqrtf(fmaxf(var, 0.f) + 1e-5f);
        a0 = gam[2 * lane] * (a0 - mu) * rs + bet[2 * lane];
        a1 = gam[2 * lane + 1] * (a1 - mu) * rs + bet[2 * lane + 1];
    }
    out[(size_t)node * 64 + lane] = f2bf(a0) | (f2bf(a1) << 16);
}

extern "C" void kernel_launch(void* const* d_in, const int* in_sizes, int n_in,
                              void* d_out, int out_size, void* d_ws, size_t ws_size,
                              hipStream_t stream) {
    const int N = in_sizes[0] / 128;
    const int E = in_sizes[1] / 2;
    const int nb = (N + 255) >> 8;
    const int* edge = (const int*)d_in[1];
    const int* srcp = edge;
    const int* dstp = edge + E;
    const float* x   = (const float*)d_in[0];
    const float* W1  = (const float*)d_in[2];
    const float* b1  = (const float*)d_in[3];
    const float* W2  = (const float*)d_in[4];
    const float* b2  = (const float*)d_in[5];
    const float* W3  = (const float*)d_in[6];
    const float* b3  = (const float*)d_in[7];
    const float* g1  = (const float*)d_in[8];
    const float* be1 = (const float*)d_in[9];
    const float* g2  = (const float*)d_in[10];
    const float* be2 = (const float*)d_in[11];
    const float* Wp1 = (const float*)d_in[12];
    const float* bp1 = (const float*)d_in[13];
    const float* Wp2 = (const float*)d_in[14];
    const float* bp2 = (const float*)d_in[15];

    char* ws = (char*)d_ws;
    size_t off = 0;
    auto alloc = [&](size_t b) -> char* {
        char* p = ws + off;
        off += (b + 255) & ~(size_t)255;
        return p;
    };
    int* bcnt   = (int*)alloc(512 * 4);
    int* bbase  = (int*)alloc((size_t)(nb + 1) * 4);
    int* cursor = (int*)alloc((size_t)nb * 4);
    int* rowptr = (int*)alloc((size_t)(N + 1) * 4);
    float* dinv = (float*)alloc((size_t)N * 4);
    u32* pairs  = (u32*)alloc((size_t)E * 4);
    int* colA   = (int*)alloc((size_t)E * 4);
    unsigned short* hw  = (unsigned short*)alloc((size_t)N * 128 * 2);
    unsigned short* hb  = (unsigned short*)alloc((size_t)N * 128 * 2);
    unsigned short* w1t = (unsigned short*)alloc(128 * 128 * 2);
    unsigned short* w2t = (unsigned short*)alloc(128 * 128 * 2);
    unsigned short* w3t = (unsigned short*)alloc(128 * 128 * 2);
    unsigned short* wp1t = (unsigned short*)alloc(128 * 128 * 2);
    unsigned short* wp2t = (unsigned short*)alloc(64 * 128 * 2);
    if (off > ws_size) return;

    int gb = (N + 63) / 64;
    int ab = (N + 3) / 4;

    hipMemsetAsync(bcnt, 0, 512 * 4, stream);
    hist_k<<<(E + 4095) / 4096, 256, 0, stream>>>(dstp, bcnt, E);
    bscan_k<<<1, 512, 0, stream>>>(bcnt, bbase, cursor, nb, E);
    bucket_k<<<(E + 8191) / 8192, 256, 0, stream>>>(srcp, dstp, cursor, pairs, E, nb);
    build_k<<<nb, 256, 0, stream>>>(pairs, bbase, rowptr, dinv, colA, N, E);
    transcvt_k<<<288, 256, 0, stream>>>(W1, W2, W3, Wp1, Wp2, w1t, w2t, w3t, wp1t, wp2t);

    gemm_k<128, false, false, true, false, true><<<gb, 256, 0, stream>>>(
        x, (const short*)w1t, nullptr, dinv, hw, N);
    agg_k<0><<<ab, 256, 0, stream>>>((const u32*)hw, rowptr, colA, dinv, b1, g1, be1,
                                     (u32*)hb, N);
    gemm_k<128, false, false, false, false, true><<<gb, 256, 0, stream>>>(
        hb, (const short*)w2t, nullptr, dinv, hw, N);
    agg_k<0><<<ab, 256, 0, stream>>>((const u32*)hw, rowptr, colA, dinv, b2, g2, be2,
                                     (u32*)hb, N);
    gemm_k<128, false, false, false, false, true><<<gb, 256, 0, stream>>>(
        hb, (const short*)w3t, nullptr, dinv, hw, N);
    agg_k<1><<<ab, 256, 0, stream>>>((const u32*)hw, rowptr, colA, dinv, b3, g1, be1,
                                     (u32*)hb, N);
    gemm_k<128, true, false, false, false, false><<<gb, 256, 0, stream>>>(
        hb, (const short*)wp1t, bp1, nullptr, hw, N);
    gemm_k<64, true, true, false, true, false><<<gb, 256, 0, stream>>>(
        hw, (const short*)wp2t, bp2, nullptr, d_out, N);
}

// Round 6
// 504.100 us; speedup vs baseline: 1.1493x; 1.0012x over previous
//
#include <hip/hip_runtime.h>
#include <hip/hip_bf16.h>

typedef __attribute__((ext_vector_type(8))) short short8;
typedef __attribute__((ext_vector_type(4))) float floatx4;
typedef unsigned int u32;

__device__ __forceinline__ float bf2f(u32 u) {
    union { u32 u; float f; } c; c.u = u << 16; return c.f;
}
__device__ __forceinline__ float bf2f_hi(u32 u) {
    union { u32 u; float f; } c; c.u = u & 0xFFFF0000u; return c.f;
}
__device__ __forceinline__ u32 f2bf(float f) {
    union { float f; u32 u; } c; c.f = f;
    return (c.u + 0x7FFFu + ((c.u >> 16) & 1u)) >> 16;  // RNE
}
__device__ __forceinline__ short8 cvt8(const float* p) {
    float4 f0 = ((const float4*)p)[0];
    float4 f1 = ((const float4*)p)[1];
    short8 r;
    r[0] = (short)f2bf(f0.x); r[1] = (short)f2bf(f0.y);
    r[2] = (short)f2bf(f0.z); r[3] = (short)f2bf(f0.w);
    r[4] = (short)f2bf(f1.x); r[5] = (short)f2bf(f1.y);
    r[6] = (short)f2bf(f1.z); r[7] = (short)f2bf(f1.w);
    return r;
}

// ---------------- CSR build: bucket sort (256 dst nodes / bucket) ----------------
// fused: blocks [0,histB) do the bucket histogram; blocks [histB, histB+288) do
// the weight transpose+bf16 convert (independent work, one dispatch).
__global__ __launch_bounds__(256) void hist_trans_k(
        const int* __restrict__ dst, int* __restrict__ bcnt, int E, int histB,
        const float* __restrict__ W1, const float* __restrict__ W2,
        const float* __restrict__ W3, const float* __restrict__ Wp1,
        const float* __restrict__ Wp2,
        unsigned short* __restrict__ o1, unsigned short* __restrict__ o2,
        unsigned short* __restrict__ o3, unsigned short* __restrict__ o4,
        unsigned short* __restrict__ o5) {
    int t = threadIdx.x;
    if ((int)blockIdx.x < histB) {
        __shared__ int h[512];
        h[t] = 0; h[t + 256] = 0;
        __syncthreads();
        int e0 = blockIdx.x * 4096;
        int ne = min(4096, E - e0);
        for (int i = t; i < ne; i += 256) atomicAdd(&h[dst[e0 + i] >> 8], 1);
        __syncthreads();
        int c = h[t];
        if (c) atomicAdd(&bcnt[t], c);
        c = h[t + 256];
        if (c) atomicAdd(&bcnt[t + 256], c);
    } else {
        int i = (blockIdx.x - histB) * 256 + t;
        const float* in; unsigned short* out; int cols, li;
        if (i < 16384)      { in = W1;  out = o1; cols = 128; li = i; }
        else if (i < 32768) { in = W2;  out = o2; cols = 128; li = i - 16384; }
        else if (i < 49152) { in = W3;  out = o3; cols = 128; li = i - 32768; }
        else if (i < 65536) { in = Wp1; out = o4; cols = 128; li = i - 49152; }
        else                { in = Wp2; out = o5; cols = 64;  li = i - 65536; }
        int r = li / cols, c = li - r * cols;
        out[(size_t)c * 128 + r] = (unsigned short)f2bf(in[li]);
    }
}

__global__ void bscan_k(const int* __restrict__ bcnt, int* __restrict__ bbase,
                        int* __restrict__ cursor, int nb, int E) {
    __shared__ int tmp[512];
    int t = threadIdx.x;
    int v = (t < nb) ? bcnt[t] : 0;
    tmp[t] = v;
    __syncthreads();
    for (int off = 1; off < 512; off <<= 1) {
        int a = (t >= off) ? tmp[t - off] : 0;
        __syncthreads();
        tmp[t] += a;
        __syncthreads();
    }
    if (t < nb) {
        int ex = tmp[t] - v;
        bbase[t] = ex;
        cursor[t] = ex;
    }
    if (t == 0) bbase[nb] = E;
}

__global__ __launch_bounds__(256) void bucket_k(const int* __restrict__ src,
                                                const int* __restrict__ dst,
                                                int* __restrict__ cursor,
                                                u32* __restrict__ pairs, int E, int nb) {
    __shared__ int cnt[512];
    __shared__ int gbase[512];
    __shared__ int cur[512];
    int t = threadIdx.x;
    cnt[t] = 0; cnt[t + 256] = 0;
    __syncthreads();
    int e0 = blockIdx.x * 8192;
    int ne = min(8192, E - e0);
    for (int i = t; i < ne; i += 256) atomicAdd(&cnt[dst[e0 + i] >> 8], 1);
    __syncthreads();
    for (int b = t; b < nb; b += 256) {
        int c = cnt[b];
        gbase[b] = c ? atomicAdd(&cursor[b], c) : 0;
        cur[b] = 0;
    }
    __syncthreads();
    for (int i = t; i < ne; i += 256) {
        int d = dst[e0 + i];
        int s = src[e0 + i];
        int b = d >> 8;
        int p = atomicAdd(&cur[b], 1);
        pairs[gbase[b] + p] = (u32)s | ((u32)(d & 255) << 24);
    }
}

// per-bucket rowptr/dinv/col build (LDS-staged for grouped coalesced writes)
#define LCOL_CAP 12288
__global__ __launch_bounds__(256) void build_k(const u32* __restrict__ pairs,
                                               const int* __restrict__ bbase,
                                               int* __restrict__ rowptr,
                                               float* __restrict__ dinv,
                                               int* __restrict__ col, int N, int E) {
    __shared__ int cnt[256], incl[256], cur[256];
    __shared__ int lcol[LCOL_CAP];
    int b = blockIdx.x, t = threadIdx.x;
    int base = bbase[b];
    int ecnt = bbase[b + 1] - base;
    cnt[t] = 0;
    __syncthreads();
    for (int j = t; j < ecnt; j += 256) atomicAdd(&cnt[pairs[base + j] >> 24], 1);
    __syncthreads();
    incl[t] = cnt[t];
    __syncthreads();
    for (int off = 1; off < 256; off <<= 1) {
        int a = (t >= off) ? incl[t - off] : 0;
        __syncthreads();
        incl[t] += a;
        __syncthreads();
    }
    int myc = cnt[t];
    int ex = incl[t] - myc;
    int node = b * 256 + t;
    if (node < N) {
        rowptr[node] = base + ex;
        dinv[node] = rsqrtf((float)myc + 1.0f);  // +1 self-loop
    }
    cur[t] = ex;
    if (b == 0 && t == 0) rowptr[N] = E;
    __syncthreads();
    if (ecnt <= LCOL_CAP) {
        for (int j = t; j < ecnt; j += 256) {
            u32 v = pairs[base + j];
            int r = atomicAdd(&cur[v >> 24], 1);
            lcol[r] = (int)(v & 0xFFFFFF);
        }
        __syncthreads();
        for (int j = t; j < ecnt; j += 256) col[base + j] = lcol[j];
    } else {  // safety fallback
        for (int j = t; j < ecnt; j += 256) {
            u32 v = pairs[base + j];
            int r = atomicAdd(&cur[v >> 24], 1);
            col[base + r] = (int)(v & 0xFFFFFF);
        }
    }
}

// ---------------- GEMM: out[M][NCOLS] = A[M][128] @ W[128][NCOLS] (Wt bf16, pre-T) ----------------
// Operand-swapped MFMA: A-operand = Wt tile, B-operand = x rows -> C[m=ncol][n=xrow].
template <int NCOLS, bool BIAS, bool SIG, bool AF32, bool OUTF32, bool DINV>
__global__ __launch_bounds__(256) void gemm_k(const void* __restrict__ Av,
                                              const short* __restrict__ Wt,
                                              const float* __restrict__ bias,
                                              const float* __restrict__ dinv,
                                              void* __restrict__ outv, int M) {
    int wave = threadIdx.x >> 6;
    int lane = threadIdx.x & 63;
    int m0 = blockIdx.x * 64 + wave * 16;
    if (m0 >= M) return;
    int quad = lane >> 4, lr = lane & 15;
    int row = m0 + lr;
    bool wr = row < M;
    if (row >= M) row = M - 1;  // clamp loads; stores guarded by wr
    short8 b0, b1, b2, b3;      // B-operand: x row fragments
    if (AF32) {
        const float* Ab = (const float*)Av + (size_t)row * 128 + quad * 8;
        b0 = cvt8(Ab); b1 = cvt8(Ab + 32); b2 = cvt8(Ab + 64); b3 = cvt8(Ab + 96);
    } else {
        const short8* Ap = (const short8*)((const short*)Av + (size_t)row * 128 + quad * 8);
        b0 = Ap[0]; b1 = Ap[4]; b2 = Ap[8]; b3 = Ap[12];
    }
    float di = DINV ? dinv[row] : 1.f;
#pragma unroll
    for (int nt = 0; nt < NCOLS / 16; ++nt) {
        int ncol = nt * 16 + lr;
        const short8* Wp = (const short8*)(Wt + (size_t)ncol * 128 + quad * 8);
        short8 a0 = Wp[0], a1 = Wp[4], a2 = Wp[8], a3 = Wp[12];
        floatx4 acc = {0.f, 0.f, 0.f, 0.f};
        acc = __builtin_amdgcn_mfma_f32_16x16x32_bf16(a0, b0, acc, 0, 0, 0);
        acc = __builtin_amdgcn_mfma_f32_16x16x32_bf16(a1, b1, acc, 0, 0, 0);
        acc = __builtin_amdgcn_mfma_f32_16x16x32_bf16(a2, b2, acc, 0, 0, 0);
        acc = __builtin_amdgcn_mfma_f32_16x16x32_bf16(a3, b3, acc, 0, 0, 0);
        int c0 = nt * 16 + quad * 4;  // 4 consecutive cols for this lane
        float4 bv4 = BIAS ? *(const float4*)(bias + c0) : float4{0.f, 0.f, 0.f, 0.f};
        float o[4];
#pragma unroll
        for (int r = 0; r < 4; ++r) {
            float v = acc[r] * di;
            if (BIAS) v += ((const float*)&bv4)[r];
            if (SIG) v = 1.f / (1.f + __expf(-v));
            o[r] = v;
        }
        if (wr) {
            if (OUTF32) {
                float4 st = {o[0], o[1], o[2], o[3]};
                *(float4*)((float*)outv + (size_t)(m0 + lr) * NCOLS + c0) = st;
            } else {
                uint2 st;
                st.x = f2bf(o[0]) | (f2bf(o[1]) << 16);
                st.y = f2bf(o[2]) | (f2bf(o[3]) << 16);
                *(uint2*)((unsigned short*)outv + (size_t)(m0 + lr) * NCOLS + c0) = st;
            }
        }
    }
}

// ---------------- fused aggregate + bias + relu (+ LayerNorm), v4 ----------------
// wave per node; lane handles feats {2*lane, 2*lane+1}.
// readlane -> uniform src index -> SALU addressing + saddr global loads.
// hw rows pre-scaled by dinv[src]; out = dinv[i]*(sum_neighbors + self) + b
template <int MODE>  // 0: relu+LN, 1: relu only
__global__ __launch_bounds__(256) void agg_k(const u32* __restrict__ hw,
                                             const int* __restrict__ rowptr,
                                             const int* __restrict__ col,
                                             const float* __restrict__ dinv,
                                             const float* __restrict__ bias,
                                             const float* __restrict__ gam,
                                             const float* __restrict__ bet,
                                             u32* __restrict__ out, int n) {
    int lane = threadIdx.x & 63;
    int node = blockIdx.x * 4 + (threadIdx.x >> 6);
    if (node >= n) return;
    int beg = rowptr[node], end = rowptr[node + 1];
    float a0 = 0.f, a1 = 0.f;
    for (int c = beg; c < end; c += 64) {
        int idx = c + lane;
        int sv = (idx < end) ? col[idx] : 0;
        int m = end - c;
        if (m > 64) m = 64;
        int e = 0;
        for (; e + 16 <= m; e += 16) {  // 16 gathers in flight, scalar-addressed
            u32 v[16];
#pragma unroll
            for (int j = 0; j < 16; ++j) {
                int s = __builtin_amdgcn_readlane(sv, e + j);  // uniform
                v[j] = hw[(size_t)s * 64 + lane];
            }
#pragma unroll
            for (int j = 0; j < 16; ++j) {
                a0 += bf2f(v[j] & 0xffff);
                a1 += bf2f_hi(v[j]);
            }
        }
        for (; e + 4 <= m; e += 4) {
            u32 v[4];
#pragma unroll
            for (int j = 0; j < 4; ++j) {
                int s = __builtin_amdgcn_readlane(sv, e + j);
                v[j] = hw[(size_t)s * 64 + lane];
            }
#pragma unroll
            for (int j = 0; j < 4; ++j) {
                a0 += bf2f(v[j] & 0xffff);
                a1 += bf2f_hi(v[j]);
            }
        }
        for (; e < m; ++e) {
            int s = __builtin_amdgcn_readlane(sv, e);
            u32 v = hw[(size_t)s * 64 + lane];
            a0 += bf2f(v & 0xffff);
            a1 += bf2f_hi(v);
        }
    }
    float di = dinv[node];
    u32 vs = hw[(size_t)node * 64 + lane];  // self (already dinv[i]-scaled)
    a0 = di * (a0 + bf2f(vs & 0xffff));
    a1 = di * (a1 + bf2f_hi(vs));
    a0 = fmaxf(a0 + bias[2 * lane], 0.f);
    a1 = fmaxf(a1 + bias[2 * lane + 1], 0.f);
    if (MODE == 0) {
        float s = a0 + a1, q = a0 * a0 + a1 * a1;
#pragma unroll
        for (int m = 32; m >= 1; m >>= 1) {
            s += __shfl_xor(s, m, 64);
            q += __shfl_xor(q, m, 64);
        }
        float mu = s * (1.f / 128.f);
        float var = q * (1.f / 128.f) - mu * mu;
        float rs = rsqrtf(fmaxf(var, 0.f) + 1e-5f);
        a0 = gam[2 * lane] * (a0 - mu) * rs + bet[2 * lane];
        a1 = gam[2 * lane + 1] * (a1 - mu) * rs + bet[2 * lane + 1];
    }
    out[(size_t)node * 64 + lane] = f2bf(a0) | (f2bf(a1) << 16);
}

extern "C" void kernel_launch(void* const* d_in, const int* in_sizes, int n_in,
                              void* d_out, int out_size, void* d_ws, size_t ws_size,
                              hipStream_t stream) {
    const int N = in_sizes[0] / 128;
    const int E = in_sizes[1] / 2;
    const int nb = (N + 255) >> 8;
    const int* edge = (const int*)d_in[1];
    const int* srcp = edge;
    const int* dstp = edge + E;
    const float* x   = (const float*)d_in[0];
    const float* W1  = (const float*)d_in[2];
    const float* b1  = (const float*)d_in[3];
    const float* W2  = (const float*)d_in[4];
    const float* b2  = (const float*)d_in[5];
    const float* W3  = (const float*)d_in[6];
    const float* b3  = (const float*)d_in[7];
    const float* g1  = (const float*)d_in[8];
    const float* be1 = (const float*)d_in[9];
    const float* g2  = (const float*)d_in[10];
    const float* be2 = (const float*)d_in[11];
    const float* Wp1 = (const float*)d_in[12];
    const float* bp1 = (const float*)d_in[13];
    const float* Wp2 = (const float*)d_in[14];
    const float* bp2 = (const float*)d_in[15];

    char* ws = (char*)d_ws;
    size_t off = 0;
    auto alloc = [&](size_t b) -> char* {
        char* p = ws + off;
        off += (b + 255) & ~(size_t)255;
        return p;
    };
    int* bcnt   = (int*)alloc(512 * 4);
    int* bbase  = (int*)alloc((size_t)(nb + 1) * 4);
    int* cursor = (int*)alloc((size_t)nb * 4);
    int* rowptr = (int*)alloc((size_t)(N + 1) * 4);
    float* dinv = (float*)alloc((size_t)N * 4);
    u32* pairs  = (u32*)alloc((size_t)E * 4);
    int* colA   = (int*)alloc((size_t)E * 4);
    unsigned short* hw  = (unsigned short*)alloc((size_t)N * 128 * 2);
    unsigned short* hb  = (unsigned short*)alloc((size_t)N * 128 * 2);
    unsigned short* w1t = (unsigned short*)alloc(128 * 128 * 2);
    unsigned short* w2t = (unsigned short*)alloc(128 * 128 * 2);
    unsigned short* w3t = (unsigned short*)alloc(128 * 128 * 2);
    unsigned short* wp1t = (unsigned short*)alloc(128 * 128 * 2);
    unsigned short* wp2t = (unsigned short*)alloc(64 * 128 * 2);
    if (off > ws_size) return;

    int gb = (N + 63) / 64;
    int ab = (N + 3) / 4;
    int histB = (E + 4095) / 4096;

    hipMemsetAsync(bcnt, 0, 512 * 4, stream);
    hist_trans_k<<<histB + 288, 256, 0, stream>>>(dstp, bcnt, E, histB,
                                                  W1, W2, W3, Wp1, Wp2,
                                                  w1t, w2t, w3t, wp1t, wp2t);
    bscan_k<<<1, 512, 0, stream>>>(bcnt, bbase, cursor, nb, E);
    bucket_k<<<(E + 8191) / 8192, 256, 0, stream>>>(srcp, dstp, cursor, pairs, E, nb);
    build_k<<<nb, 256, 0, stream>>>(pairs, bbase, rowptr, dinv, colA, N, E);

    gemm_k<128, false, false, true, false, true><<<gb, 256, 0, stream>>>(
        x, (const short*)w1t, nullptr, dinv, hw, N);
    agg_k<0><<<ab, 256, 0, stream>>>((const u32*)hw, rowptr, colA, dinv, b1, g1, be1,
                                     (u32*)hb, N);
    gemm_k<128, false, false, false, false, true><<<gb, 256, 0, stream>>>(
        hb, (const short*)w2t, nullptr, dinv, hw, N);
    agg_k<0><<<ab, 256, 0, stream>>>((const u32*)hw, rowptr, colA, dinv, b2, g2, be2,
                                     (u32*)hb, N);
    gemm_k<128, false, false, false, false, true><<<gb, 256, 0, stream>>>(
        hb, (const short*)w3t, nullptr, dinv, hw, N);
    agg_k<1><<<ab, 256, 0, stream>>>((const u32*)hw, rowptr, colA, dinv, b3, g1, be1,
                                     (u32*)hb, N);
    gemm_k<128, true, false, false, false, false><<<gb, 256, 0, stream>>>(
        hb, (const short*)wp1t, bp1, nullptr, hw, N);
    gemm_k<64, true, true, false, true, false><<<gb, 256, 0, stream>>>(
        hw, (const short*)wp2t, bp2, nullptr, d_out, N);
}

// Round 7
// 460.770 us; speedup vs baseline: 1.2574x; 1.0940x over previous
//
#include <hip/hip_runtime.h>
#include <hip/hip_bf16.h>

typedef __attribute__((ext_vector_type(8))) short short8;
typedef __attribute__((ext_vector_type(4))) float floatx4;
typedef unsigned int u32;

__device__ __forceinline__ float bf2f(u32 u) {
    union { u32 u; float f; } c; c.u = u << 16; return c.f;
}
__device__ __forceinline__ float bf2f_hi(u32 u) {
    union { u32 u; float f; } c; c.u = u & 0xFFFF0000u; return c.f;
}
__device__ __forceinline__ u32 f2bf(float f) {
    union { float f; u32 u; } c; c.f = f;
    return (c.u + 0x7FFFu + ((c.u >> 16) & 1u)) >> 16;  // RNE
}
__device__ __forceinline__ short8 cvt8(const float* p) {
    float4 f0 = ((const float4*)p)[0];
    float4 f1 = ((const float4*)p)[1];
    short8 r;
    r[0] = (short)f2bf(f0.x); r[1] = (short)f2bf(f0.y);
    r[2] = (short)f2bf(f0.z); r[3] = (short)f2bf(f0.w);
    r[4] = (short)f2bf(f1.x); r[5] = (short)f2bf(f1.y);
    r[6] = (short)f2bf(f1.z); r[7] = (short)f2bf(f1.w);
    return r;
}

// gather + accumulate one node's neighborhood; lane holds feats {2*lane,2*lane+1}
__device__ __forceinline__ void gather_row(const u32* __restrict__ hw,
                                           const int* __restrict__ col,
                                           int beg, int end, int lane,
                                           float& a0, float& a1) {
    for (int c = beg; c < end; c += 64) {
        int idx = c + lane;
        int sv = (idx < end) ? col[idx] : 0;
        int m = end - c;
        if (m > 64) m = 64;
        int e = 0;
        for (; e + 16 <= m; e += 16) {
            u32 v[16];
#pragma unroll
            for (int j = 0; j < 16; ++j) {
                int s = __builtin_amdgcn_readlane(sv, e + j);
                v[j] = hw[(size_t)s * 64 + lane];
            }
#pragma unroll
            for (int j = 0; j < 16; ++j) {
                a0 += bf2f(v[j] & 0xffff);
                a1 += bf2f_hi(v[j]);
            }
        }
        for (; e + 4 <= m; e += 4) {
            u32 v[4];
#pragma unroll
            for (int j = 0; j < 4; ++j) {
                int s = __builtin_amdgcn_readlane(sv, e + j);
                v[j] = hw[(size_t)s * 64 + lane];
            }
#pragma unroll
            for (int j = 0; j < 4; ++j) {
                a0 += bf2f(v[j] & 0xffff);
                a1 += bf2f_hi(v[j]);
            }
        }
        for (; e < m; ++e) {
            int s = __builtin_amdgcn_readlane(sv, e);
            u32 v = hw[(size_t)s * 64 + lane];
            a0 += bf2f(v & 0xffff);
            a1 += bf2f_hi(v);
        }
    }
}

// ---------------- CSR build ----------------
__global__ __launch_bounds__(256) void hist_trans_k(
        const int* __restrict__ dst, int* __restrict__ bcnt, int E, int histB,
        const float* __restrict__ W1, const float* __restrict__ W2,
        const float* __restrict__ W3, const float* __restrict__ Wp1,
        const float* __restrict__ Wp2,
        unsigned short* __restrict__ o1, unsigned short* __restrict__ o2,
        unsigned short* __restrict__ o3, unsigned short* __restrict__ o4,
        unsigned short* __restrict__ o5) {
    int t = threadIdx.x;
    if ((int)blockIdx.x < histB) {
        __shared__ int h[512];
        h[t] = 0; h[t + 256] = 0;
        __syncthreads();
        int e0 = blockIdx.x * 4096;
        int ne = min(4096, E - e0);
        for (int i = t; i < ne; i += 256) atomicAdd(&h[dst[e0 + i] >> 8], 1);
        __syncthreads();
        int c = h[t];
        if (c) atomicAdd(&bcnt[t], c);
        c = h[t + 256];
        if (c) atomicAdd(&bcnt[t + 256], c);
    } else {
        int i = (blockIdx.x - histB) * 256 + t;
        const float* in; unsigned short* out; int cols, li;
        if (i < 16384)      { in = W1;  out = o1; cols = 128; li = i; }
        else if (i < 32768) { in = W2;  out = o2; cols = 128; li = i - 16384; }
        else if (i < 49152) { in = W3;  out = o3; cols = 128; li = i - 32768; }
        else if (i < 65536) { in = Wp1; out = o4; cols = 128; li = i - 49152; }
        else                { in = Wp2; out = o5; cols = 64;  li = i - 65536; }
        int r = li / cols, c = li - r * cols;
        out[(size_t)c * 128 + r] = (unsigned short)f2bf(in[li]);
    }
}

__global__ void bscan_k(const int* __restrict__ bcnt, int* __restrict__ bbase,
                        int* __restrict__ cursor, int nb, int E) {
    __shared__ int tmp[512];
    int t = threadIdx.x;
    int v = (t < nb) ? bcnt[t] : 0;
    tmp[t] = v;
    __syncthreads();
    for (int off = 1; off < 512; off <<= 1) {
        int a = (t >= off) ? tmp[t - off] : 0;
        __syncthreads();
        tmp[t] += a;
        __syncthreads();
    }
    if (t < nb) {
        int ex = tmp[t] - v;
        bbase[t] = ex;
        cursor[t] = ex;
    }
    if (t == 0) bbase[nb] = E;
}

__global__ __launch_bounds__(256) void bucket_k(const int* __restrict__ src,
                                                const int* __restrict__ dst,
                                                int* __restrict__ cursor,
                                                u32* __restrict__ pairs, int E, int nb) {
    __shared__ int cnt[512];
    __shared__ int gbase[512];
    __shared__ int cur[512];
    int t = threadIdx.x;
    cnt[t] = 0; cnt[t + 256] = 0;
    __syncthreads();
    int e0 = blockIdx.x * 8192;
    int ne = min(8192, E - e0);
    for (int i = t; i < ne; i += 256) atomicAdd(&cnt[dst[e0 + i] >> 8], 1);
    __syncthreads();
    for (int b = t; b < nb; b += 256) {
        int c = cnt[b];
        gbase[b] = c ? atomicAdd(&cursor[b], c) : 0;
        cur[b] = 0;
    }
    __syncthreads();
    for (int i = t; i < ne; i += 256) {
        int d = dst[e0 + i];
        int s = src[e0 + i];
        int b = d >> 8;
        int p = atomicAdd(&cur[b], 1);
        pairs[gbase[b] + p] = (u32)s | ((u32)(d & 255) << 24);
    }
}

#define LCOL_CAP 12288
__global__ __launch_bounds__(256) void build_k(const u32* __restrict__ pairs,
                                               const int* __restrict__ bbase,
                                               int* __restrict__ rowptr,
                                               float* __restrict__ dinv,
                                               int* __restrict__ col, int N, int E) {
    __shared__ int cnt[256], incl[256], cur[256];
    __shared__ int lcol[LCOL_CAP];
    int b = blockIdx.x, t = threadIdx.x;
    int base = bbase[b];
    int ecnt = bbase[b + 1] - base;
    cnt[t] = 0;
    __syncthreads();
    for (int j = t; j < ecnt; j += 256) atomicAdd(&cnt[pairs[base + j] >> 24], 1);
    __syncthreads();
    incl[t] = cnt[t];
    __syncthreads();
    for (int off = 1; off < 256; off <<= 1) {
        int a = (t >= off) ? incl[t - off] : 0;
        __syncthreads();
        incl[t] += a;
        __syncthreads();
    }
    int myc = cnt[t];
    int ex = incl[t] - myc;
    int node = b * 256 + t;
    if (node < N) {
        rowptr[node] = base + ex;
        dinv[node] = rsqrtf((float)myc + 1.0f);  // +1 self-loop
    }
    cur[t] = ex;
    if (b == 0 && t == 0) rowptr[N] = E;
    __syncthreads();
    if (ecnt <= LCOL_CAP) {
        for (int j = t; j < ecnt; j += 256) {
            u32 v = pairs[base + j];
            int r = atomicAdd(&cur[v >> 24], 1);
            lcol[r] = (int)(v & 0xFFFFFF);
        }
        __syncthreads();
        for (int j = t; j < ecnt; j += 256) col[base + j] = lcol[j];
    } else {
        for (int j = t; j < ecnt; j += 256) {
            u32 v = pairs[base + j];
            int r = atomicAdd(&cur[v >> 24], 1);
            col[base + r] = (int)(v & 0xFFFFFF);
        }
    }
}

// ---------------- GEMM (only for layer 1: x f32 -> hw bf16, dinv-scaled) ----------------
__global__ __launch_bounds__(256) void gemm1_k(const float* __restrict__ A,
                                               const short* __restrict__ Wt,
                                               const float* __restrict__ dinv,
                                               unsigned short* __restrict__ out, int M) {
    int wave = threadIdx.x >> 6;
    int lane = threadIdx.x & 63;
    int m0 = blockIdx.x * 64 + wave * 16;
    if (m0 >= M) return;
    int quad = lane >> 4, lr = lane & 15;
    int row = m0 + lr;
    bool wr = row < M;
    if (row >= M) row = M - 1;
    const float* Ab = A + (size_t)row * 128 + quad * 8;
    short8 b0 = cvt8(Ab), b1 = cvt8(Ab + 32), b2 = cvt8(Ab + 64), b3 = cvt8(Ab + 96);
    float di = dinv[row];
#pragma unroll
    for (int nt = 0; nt < 8; ++nt) {
        int ncol = nt * 16 + lr;
        const short8* Wp = (const short8*)(Wt + (size_t)ncol * 128 + quad * 8);
        short8 a0 = Wp[0], a1 = Wp[4], a2 = Wp[8], a3 = Wp[12];
        floatx4 acc = {0.f, 0.f, 0.f, 0.f};
        acc = __builtin_amdgcn_mfma_f32_16x16x32_bf16(a0, b0, acc, 0, 0, 0);
        acc = __builtin_amdgcn_mfma_f32_16x16x32_bf16(a1, b1, acc, 0, 0, 0);
        acc = __builtin_amdgcn_mfma_f32_16x16x32_bf16(a2, b2, acc, 0, 0, 0);
        acc = __builtin_amdgcn_mfma_f32_16x16x32_bf16(a3, b3, acc, 0, 0, 0);
        int c0 = nt * 16 + quad * 4;
        if (wr) {
            uint2 st;
            st.x = f2bf(acc[0] * di) | (f2bf(acc[1] * di) << 16);
            st.y = f2bf(acc[2] * di) | (f2bf(acc[3] * di) << 16);
            *(uint2*)(out + (size_t)(m0 + lr) * 128 + c0) = st;
        }
    }
}

// ---------------- fused conv: agg + bias + relu + LN + @Wnext*dinv ----------------
// block = 16 nodes (4/wave); LDS-staged rows; MFMA tail (2 col-tiles/wave).
__global__ __launch_bounds__(256) void fconv_k(const u32* __restrict__ hw,
                                               const int* __restrict__ rowptr,
                                               const int* __restrict__ col,
                                               const float* __restrict__ dinv,
                                               const float* __restrict__ bias,
                                               const float* __restrict__ gam,
                                               const float* __restrict__ bet,
                                               const short* __restrict__ Wt,
                                               unsigned short* __restrict__ out, int N) {
    __shared__ unsigned short rows[16][136];  // 272B stride: 16B-aligned, 2-way banks
    int t = threadIdx.x, wave = t >> 6, lane = t & 63;
    int nb0 = blockIdx.x * 16;
    for (int i = 0; i < 4; ++i) {
        int r = wave * 4 + i;
        int node = nb0 + r;
        float a0 = 0.f, a1 = 0.f;
        if (node < N) {
            int beg = rowptr[node], end = rowptr[node + 1];
            gather_row(hw, col, beg, end, lane, a0, a1);
            float di = dinv[node];
            u32 vs = hw[(size_t)node * 64 + lane];
            a0 = di * (a0 + bf2f(vs & 0xffff));
            a1 = di * (a1 + bf2f_hi(vs));
            a0 = fmaxf(a0 + bias[2 * lane], 0.f);
            a1 = fmaxf(a1 + bias[2 * lane + 1], 0.f);
            float s = a0 + a1, q = a0 * a0 + a1 * a1;
#pragma unroll
            for (int m = 32; m >= 1; m >>= 1) {
                s += __shfl_xor(s, m, 64);
                q += __shfl_xor(q, m, 64);
            }
            float mu = s * (1.f / 128.f);
            float var = q * (1.f / 128.f) - mu * mu;
            float rs = rsqrtf(fmaxf(var, 0.f) + 1e-5f);
            a0 = gam[2 * lane] * (a0 - mu) * rs + bet[2 * lane];
            a1 = gam[2 * lane + 1] * (a1 - mu) * rs + bet[2 * lane + 1];
        }
        ((u32*)&rows[r][0])[lane] = f2bf(a0) | (f2bf(a1) << 16);
    }
    __syncthreads();
    int quad = lane >> 4, lr = lane & 15;
    short8 b0 = *(const short8*)&rows[lr][quad * 8];
    short8 b1 = *(const short8*)&rows[lr][32 + quad * 8];
    short8 b2 = *(const short8*)&rows[lr][64 + quad * 8];
    short8 b3 = *(const short8*)&rows[lr][96 + quad * 8];
    int onode = nb0 + lr;
    float di2 = (onode < N) ? dinv[onode] : 0.f;
#pragma unroll
    for (int k = 0; k < 2; ++k) {
        int ct = wave * 2 + k;
        int ncol = ct * 16 + lr;
        const short8* Wp = (const short8*)(Wt + (size_t)ncol * 128 + quad * 8);
        short8 a0 = Wp[0], a1 = Wp[4], a2 = Wp[8], a3 = Wp[12];
        floatx4 acc = {0.f, 0.f, 0.f, 0.f};
        acc = __builtin_amdgcn_mfma_f32_16x16x32_bf16(a0, b0, acc, 0, 0, 0);
        acc = __builtin_amdgcn_mfma_f32_16x16x32_bf16(a1, b1, acc, 0, 0, 0);
        acc = __builtin_amdgcn_mfma_f32_16x16x32_bf16(a2, b2, acc, 0, 0, 0);
        acc = __builtin_amdgcn_mfma_f32_16x16x32_bf16(a3, b3, acc, 0, 0, 0);
        int c0 = ct * 16 + quad * 4;
        if (onode < N) {
            uint2 st;
            st.x = f2bf(acc[0] * di2) | (f2bf(acc[1] * di2) << 16);
            st.y = f2bf(acc[2] * di2) | (f2bf(acc[3] * di2) << 16);
            *(uint2*)(out + (size_t)onode * 128 + c0) = st;
        }
    }
}

// ---------------- fused head: agg + b3 + relu + @Wp1+bp1 + @Wp2+bp2 + sigmoid ----------------
__global__ __launch_bounds__(256) void fhead_k(const u32* __restrict__ hw,
                                               const int* __restrict__ rowptr,
                                               const int* __restrict__ col,
                                               const float* __restrict__ dinv,
                                               const float* __restrict__ bias,
                                               const short* __restrict__ Wp1t,
                                               const float* __restrict__ bp1,
                                               const short* __restrict__ Wp2t,
                                               const float* __restrict__ bp2,
                                               float* __restrict__ out, int N) {
    __shared__ unsigned short rows[16][136];
    __shared__ unsigned short h1s[16][136];
    int t = threadIdx.x, wave = t >> 6, lane = t & 63;
    int nb0 = blockIdx.x * 16;
    for (int i = 0; i < 4; ++i) {
        int r = wave * 4 + i;
        int node = nb0 + r;
        float a0 = 0.f, a1 = 0.f;
        if (node < N) {
            int beg = rowptr[node], end = rowptr[node + 1];
            gather_row(hw, col, beg, end, lane, a0, a1);
            float di = dinv[node];
            u32 vs = hw[(size_t)node * 64 + lane];
            a0 = di * (a0 + bf2f(vs & 0xffff));
            a1 = di * (a1 + bf2f_hi(vs));
            a0 = fmaxf(a0 + bias[2 * lane], 0.f);
            a1 = fmaxf(a1 + bias[2 * lane + 1], 0.f);
        }
        ((u32*)&rows[r][0])[lane] = f2bf(a0) | (f2bf(a1) << 16);
    }
    __syncthreads();
    int quad = lane >> 4, lr = lane & 15;
    {   // h1 = h @ Wp1 + bp1  (2 col-tiles per wave)
        short8 b0 = *(const short8*)&rows[lr][quad * 8];
        short8 b1 = *(const short8*)&rows[lr][32 + quad * 8];
        short8 b2 = *(const short8*)&rows[lr][64 + quad * 8];
        short8 b3 = *(const short8*)&rows[lr][96 + quad * 8];
#pragma unroll
        for (int k = 0; k < 2; ++k) {
            int ct = wave * 2 + k;
            int ncol = ct * 16 + lr;
            const short8* Wp = (const short8*)(Wp1t + (size_t)ncol * 128 + quad * 8);
            short8 a0 = Wp[0], a1 = Wp[4], a2 = Wp[8], a3 = Wp[12];
            floatx4 acc = {0.f, 0.f, 0.f, 0.f};
            acc = __builtin_amdgcn_mfma_f32_16x16x32_bf16(a0, b0, acc, 0, 0, 0);
            acc = __builtin_amdgcn_mfma_f32_16x16x32_bf16(a1, b1, acc, 0, 0, 0);
            acc = __builtin_amdgcn_mfma_f32_16x16x32_bf16(a2, b2, acc, 0, 0, 0);
            acc = __builtin_amdgcn_mfma_f32_16x16x32_bf16(a3, b3, acc, 0, 0, 0);
            int c0 = ct * 16 + quad * 4;
            float4 bv = *(const float4*)(bp1 + c0);
            uint2 st;
            st.x = f2bf(acc[0] + bv.x) | (f2bf(acc[1] + bv.y) << 16);
            st.y = f2bf(acc[2] + bv.z) | (f2bf(acc[3] + bv.w) << 16);
            *(uint2*)&h1s[lr][c0] = st;
        }
    }
    __syncthreads();
    {   // out = sigmoid(h1 @ Wp2 + bp2)  (1 col-tile per wave; 64 cols total)
        short8 b0 = *(const short8*)&h1s[lr][quad * 8];
        short8 b1 = *(const short8*)&h1s[lr][32 + quad * 8];
        short8 b2 = *(const short8*)&h1s[lr][64 + quad * 8];
        short8 b3 = *(const short8*)&h1s[lr][96 + quad * 8];
        int ncol = wave * 16 + lr;
        const short8* Wp = (const short8*)(Wp2t + (size_t)ncol * 128 + quad * 8);
        short8 a0 = Wp[0], a1 = Wp[4], a2 = Wp[8], a3 = Wp[12];
        floatx4 acc = {0.f, 0.f, 0.f, 0.f};
        acc = __builtin_amdgcn_mfma_f32_16x16x32_bf16(a0, b0, acc, 0, 0, 0);
        acc = __builtin_amdgcn_mfma_f32_16x16x32_bf16(a1, b1, acc, 0, 0, 0);
        acc = __builtin_amdgcn_mfma_f32_16x16x32_bf16(a2, b2, acc, 0, 0, 0);
        acc = __builtin_amdgcn_mfma_f32_16x16x32_bf16(a3, b3, acc, 0, 0, 0);
        int c0 = wave * 16 + quad * 4;
        int onode = nb0 + lr;
        if (onode < N) {
            float4 bv = *(const float4*)(bp2 + c0);
            float4 st;
            st.x = 1.f / (1.f + __expf(-(acc[0] + bv.x)));
            st.y = 1.f / (1.f + __expf(-(acc[1] + bv.y)));
            st.z = 1.f / (1.f + __expf(-(acc[2] + bv.z)));
            st.w = 1.f / (1.f + __expf(-(acc[3] + bv.w)));
            *(float4*)(out + (size_t)onode * 64 + c0) = st;
        }
    }
}

extern "C" void kernel_launch(void* const* d_in, const int* in_sizes, int n_in,
                              void* d_out, int out_size, void* d_ws, size_t ws_size,
                              hipStream_t stream) {
    const int N = in_sizes[0] / 128;
    const int E = in_sizes[1] / 2;
    const int nb = (N + 255) >> 8;
    const int* edge = (const int*)d_in[1];
    const int* srcp = edge;
    const int* dstp = edge + E;
    const float* x   = (const float*)d_in[0];
    const float* W1  = (const float*)d_in[2];
    const float* b1  = (const float*)d_in[3];
    const float* W2  = (const float*)d_in[4];
    const float* b2  = (const float*)d_in[5];
    const float* W3  = (const float*)d_in[6];
    const float* b3  = (const float*)d_in[7];
    const float* g1  = (const float*)d_in[8];
    const float* be1 = (const float*)d_in[9];
    const float* g2  = (const float*)d_in[10];
    const float* be2 = (const float*)d_in[11];
    const float* Wp1 = (const float*)d_in[12];
    const float* bp1 = (const float*)d_in[13];
    const float* Wp2 = (const float*)d_in[14];
    const float* bp2 = (const float*)d_in[15];

    char* ws = (char*)d_ws;
    size_t off = 0;
    auto alloc = [&](size_t b) -> char* {
        char* p = ws + off;
        off += (b + 255) & ~(size_t)255;
        return p;
    };
    int* bcnt   = (int*)alloc(512 * 4);
    int* bbase  = (int*)alloc((size_t)(nb + 1) * 4);
    int* cursor = (int*)alloc((size_t)nb * 4);
    int* rowptr = (int*)alloc((size_t)(N + 1) * 4);
    float* dinv = (float*)alloc((size_t)N * 4);
    u32* pairs  = (u32*)alloc((size_t)E * 4);
    int* colA   = (int*)alloc((size_t)E * 4);
    unsigned short* hw  = (unsigned short*)alloc((size_t)N * 128 * 2);
    unsigned short* hb  = (unsigned short*)alloc((size_t)N * 128 * 2);
    unsigned short* w1t = (unsigned short*)alloc(128 * 128 * 2);
    unsigned short* w2t = (unsigned short*)alloc(128 * 128 * 2);
    unsigned short* w3t = (unsigned short*)alloc(128 * 128 * 2);
    unsigned short* wp1t = (unsigned short*)alloc(128 * 128 * 2);
    unsigned short* wp2t = (unsigned short*)alloc(64 * 128 * 2);
    if (off > ws_size) return;

    int gb = (N + 63) / 64;
    int fb = (N + 15) / 16;
    int histB = (E + 4095) / 4096;

    hipMemsetAsync(bcnt, 0, 512 * 4, stream);
    hist_trans_k<<<histB + 288, 256, 0, stream>>>(dstp, bcnt, E, histB,
                                                  W1, W2, W3, Wp1, Wp2,
                                                  w1t, w2t, w3t, wp1t, wp2t);
    bscan_k<<<1, 512, 0, stream>>>(bcnt, bbase, cursor, nb, E);
    bucket_k<<<(E + 8191) / 8192, 256, 0, stream>>>(srcp, dstp, cursor, pairs, E, nb);
    build_k<<<nb, 256, 0, stream>>>(pairs, bbase, rowptr, dinv, colA, N, E);

    // K1: hw = (x@W1)*dinv
    gemm1_k<<<gb, 256, 0, stream>>>(x, (const short*)w1t, dinv, hw, N);
    // K2: hb = (LN(relu(agg(hw)+b1)) @ W2)*dinv
    fconv_k<<<fb, 256, 0, stream>>>((const u32*)hw, rowptr, colA, dinv, b1, g1, be1,
                                    (const short*)w2t, hb, N);
    // K3: hw = (LN(relu(agg(hb)+b2)) @ W3)*dinv
    fconv_k<<<fb, 256, 0, stream>>>((const u32*)hb, rowptr, colA, dinv, b2, g2, be2,
                                    (const short*)w3t, hw, N);
    // K4: out = sigmoid((relu(agg(hw)+b3) @ Wp1 + bp1) @ Wp2 + bp2)
    fhead_k<<<fb, 256, 0, stream>>>((const u32*)hw, rowptr, colA, dinv, b3,
                                    (const short*)wp1t, bp1, (const short*)wp2t, bp2,
                                    (float*)d_out, N);
}